// Round 1
// 1142.028 us; speedup vs baseline: 1.1139x; 1.1139x over previous
//
#include <hip/hip_runtime.h>

#define DD 64
#define NPART 8

// ---------- batched CSR build over concatenated destination row space ----------
// Segments (global row offsets): A entity[0,180k) B user[180k,330k) C item[330k,380k) D user[380k,480k)
//
// Both scatter passes (hist, fill) are partitioned into 8 block-groups, one per
// XCD (blockIdx.x & 7 -> XCD via round-robin dispatch). Each group streams the
// FULL edge list with nontemporal loads but only touches destinations in its
// row range, so its scattered atomics/stores stay resident in its own L2
// (~2.75 MB payload window < 4 MB L2) and each 64B line is evicted once
// instead of ~16 partial-line RMW evictions.

__global__ void hist_part(const int* __restrict__ dA, const int* __restrict__ dB,
                          const int* __restrict__ dC, const int* __restrict__ dD,
                          int nA, int nB, int nC, int nD,
                          int offA, int offB, int offC, int offD,
                          int rows_per_part, int* __restrict__ counts) {
    int p = blockIdx.x & (NPART - 1);
    int lo = p * rows_per_part, hi = lo + rows_per_part;
    int tid = (blockIdx.x >> 3) * blockDim.x + threadIdx.x;
    int nthr = (gridDim.x >> 3) * blockDim.x;
    int Etot = nA + nB + nC + nD;
    for (int i = tid; i < Etot; i += nthr) {
        int j = i, g;
        if (j < nA)              g = offA + __builtin_nontemporal_load(dA + j);
        else if ((j -= nA) < nB) g = offB + __builtin_nontemporal_load(dB + j);
        else if ((j -= nB) < nC) g = offC + __builtin_nontemporal_load(dC + j);
        else { j -= nC;          g = offD + __builtin_nontemporal_load(dD + j); }
        if (g >= lo && g < hi) atomicAdd(&counts[g], 1);
    }
}

// Exclusive scan, 1024 elems per block (256 thr x 4). Per-block totals -> bsums.
__global__ void scan_blocks(const int* __restrict__ in, int* __restrict__ out,
                            int* __restrict__ bsums, int n) {
    __shared__ int ts[256];
    int base = blockIdx.x * 1024;
    int t = threadIdx.x;
    int v[4];
    int loc = 0;
#pragma unroll
    for (int k = 0; k < 4; ++k) {
        int i = base + t * 4 + k;
        v[k] = (i < n) ? in[i] : 0;
        loc += v[k];
    }
    ts[t] = loc;
    __syncthreads();
    for (int off = 1; off < 256; off <<= 1) {
        int x = (t >= off) ? ts[t - off] : 0;
        __syncthreads();
        ts[t] += x;
        __syncthreads();
    }
    if (t == 255) bsums[blockIdx.x] = ts[255];
    int run = (t == 0) ? 0 : ts[t - 1];
#pragma unroll
    for (int k = 0; k < 4; ++k) {
        int i = base + t * 4 + k;
        if (i < n) out[i] = run;
        run += v[k];
    }
}

// Exclusive scan of block sums, one 512-thread block (nb <= 512).
__global__ void scan_sums(int* __restrict__ bsums, int nb) {
    __shared__ int ts[512];
    int t = threadIdx.x;
    int v = (t < nb) ? bsums[t] : 0;
    ts[t] = v;
    __syncthreads();
    for (int off = 1; off < 512; off <<= 1) {
        int x = (t >= off) ? ts[t - off] : 0;
        __syncthreads();
        ts[t] += x;
        __syncthreads();
    }
    if (t < nb) bsums[t] = ts[t] - v;   // exclusive
}

__global__ void add_offsets(int* __restrict__ out, const int* __restrict__ bsums, int n) {
    int i = blockIdx.x * blockDim.x + threadIdx.x;
    if (i < n) out[i] += bsums[i >> 10];
}

// Edge-balanced partition boundaries over the row space: bounds[p] = first row g
// whose start position rowptr[g] >= p*Etot/8. Payload window per partition is
// then ~Etot/8*4B ~ 2.75MB, L2-resident on one XCD.
__global__ void find_bounds(const int* __restrict__ rowptr, int R, int Etot,
                            int* __restrict__ bounds) {
    int p = threadIdx.x;
    if (p > NPART) return;
    if (p == 0) { bounds[0] = 0; return; }
    if (p == NPART) { bounds[NPART] = R; return; }
    int T = (int)(((long long)Etot * p) / NPART);
    int lo = 0, hi = R;   // first g with rowptr[g] >= T
    while (lo < hi) {
        int mid = (lo + hi) >> 1;
        if (rowptr[mid] >= T) hi = mid; else lo = mid + 1;
    }
    bounds[p] = lo;
}

// pay[pos] = src | (type<<20); consumes rowptr as cursor (after: rowptr[w] = row end).
__global__ void fill_part(const int* __restrict__ dA, const int* __restrict__ sA, const int* __restrict__ tA,
                          const int* __restrict__ dB, const int* __restrict__ sB, const int* __restrict__ tB,
                          const int* __restrict__ dC, const int* __restrict__ sC,
                          const int* __restrict__ dD, const int* __restrict__ sD,
                          int nA, int nB, int nC, int nD,
                          int offA, int offB, int offC, int offD,
                          const int* __restrict__ bounds,
                          int* __restrict__ rowptr, int* __restrict__ pay) {
    int p = blockIdx.x & (NPART - 1);
    int lo = bounds[p], hi = bounds[p + 1];
    int tid = (blockIdx.x >> 3) * blockDim.x + threadIdx.x;
    int nthr = (gridDim.x >> 3) * blockDim.x;
    int Etot = nA + nB + nC + nD;
    for (int i = tid; i < Etot; i += nthr) {
        int j = i, g;
        const int* s;
        const int* tp = nullptr;
        if (j < nA)              { g = offA + __builtin_nontemporal_load(dA + j); s = sA; tp = tA; }
        else if ((j -= nA) < nB) { g = offB + __builtin_nontemporal_load(dB + j); s = sB; tp = tB; }
        else if ((j -= nB) < nC) { g = offC + __builtin_nontemporal_load(dC + j); s = sC; }
        else { j -= nC;            g = offD + __builtin_nontemporal_load(dD + j); s = sD; }
        if (g < lo || g >= hi) continue;
        int sv = __builtin_nontemporal_load(s + j);
        int t = tp ? __builtin_nontemporal_load(tp + j) : 0;
        int pos = atomicAdd(&rowptr[g], 1);
        pay[pos] = sv | (t << 20);   // normal store: we WANT it cached in local L2
    }
}

// ---------- combined gather-reduce ----------
// One wave per global destination row. Payloads fetched 64-at-a-time with one
// coalesced per-lane load, broadcast via shfl; edge loop unrolled x4 for MLP.
__global__ void gather_all(const float* __restrict__ entity_emb,
                           const float* __restrict__ user_emb,
                           const float* __restrict__ weight,
                           const int* __restrict__ rowptr, const int* __restrict__ pay,
                           float* __restrict__ kg_item, float* __restrict__ ent_out,
                           float* __restrict__ ukg, float* __restrict__ usr_out,
                           float* __restrict__ iu, float* __restrict__ ui,
                           int offB, int offC, int offD, int n_rows,
                           int n_items, int n_users) {
    int w = blockIdx.x * (blockDim.x >> 6) + (threadIdx.x >> 6);
    int lane = threadIdx.x & 63;
    if (w >= n_rows) return;

    const float* emb;
    float* dst;
    int r;
    if (w < offB)      { r = w;        emb = entity_emb; dst = (r < n_items) ? kg_item + ((size_t)r * DD)
                                                                             : ent_out + ((size_t)r * DD); }
    else if (w < offC) { r = w - offB; emb = user_emb;   dst = (r < n_users) ? ukg + ((size_t)r * DD)
                                                                             : usr_out + ((size_t)r * DD); }
    else if (w < offD) { r = w - offC; emb = user_emb;   dst = iu + ((size_t)r * DD); }
    else               { r = w - offD; emb = entity_emb; dst = ui + ((size_t)r * DD); }

    int start = (w == 0) ? 0 : rowptr[w - 1];
    int end = rowptr[w];
    float acc = 0.f;
    for (int base = start; base < end; base += 64) {
        int m = end - base; if (m > 64) m = 64;
        int p = (lane < m) ? pay[base + lane] : 0;
        int j = 0;
        for (; j + 4 <= m; j += 4) {
            int p0 = __shfl(p, j, 64), p1 = __shfl(p, j + 1, 64);
            int p2 = __shfl(p, j + 2, 64), p3 = __shfl(p, j + 3, 64);
            float e0 = emb[((p0 & 0xFFFFF) << 6) + lane];
            float w0 = weight[((p0 >> 20) << 6) + lane];
            float e1 = emb[((p1 & 0xFFFFF) << 6) + lane];
            float w1 = weight[((p1 >> 20) << 6) + lane];
            float e2 = emb[((p2 & 0xFFFFF) << 6) + lane];
            float w2 = weight[((p2 >> 20) << 6) + lane];
            float e3 = emb[((p3 & 0xFFFFF) << 6) + lane];
            float w3 = weight[((p3 >> 20) << 6) + lane];
            acc += e0 * w0; acc += e1 * w1; acc += e2 * w2; acc += e3 * w3;
        }
        for (; j < m; ++j) {
            int pj = __shfl(p, j, 64);
            acc += emb[((pj & 0xFFFFF) << 6) + lane] * weight[((pj >> 20) << 6) + lane];
        }
    }
    int deg = end - start;
    dst[lane] = acc / (float)(deg > 0 ? deg : 1);
}

// ---------- gated fusion ----------
__global__ void gate_fuse_kernel(const float* __restrict__ a_, const float* __restrict__ b_,
                                 const float* __restrict__ gA, const float* __restrict__ gB,
                                 float* __restrict__ out, int n_rows) {
    __shared__ float GA[DD][DD + 1];   // GA[k][d] = gA[d][k]
    __shared__ float GB[DD][DD + 1];
    for (int i = threadIdx.x; i < DD * DD; i += blockDim.x) {
        int d = i >> 6, k = i & 63;
        GA[k][d] = gA[i];
        GB[k][d] = gB[i];
    }
    __syncthreads();
    int lane = threadIdx.x & 63;
    int waves_per_blk = blockDim.x >> 6;
    int row0 = blockIdx.x * waves_per_blk + (threadIdx.x >> 6);
    int stride = gridDim.x * waves_per_blk;
    for (int row = row0; row < n_rows; row += stride) {
        float a = a_[(size_t)row * DD + lane];
        float b = b_[(size_t)row * DD + lane];
        float z = 0.f;
#pragma unroll
        for (int k = 0; k < DD; ++k) {
            float ak = __shfl(a, k, 64);
            float bk = __shfl(b, k, 64);
            z += ak * GA[k][lane] + bk * GB[k][lane];
        }
        float g = 1.f / (1.f + expf(-z));
        out[(size_t)row * DD + lane] = g * a + (1.f - g) * b;
    }
}

extern "C" void kernel_launch(void* const* d_in, const int* in_sizes, int n_in,
                              void* d_out, int out_size, void* d_ws, size_t ws_size,
                              hipStream_t stream) {
    const float* entity_emb = (const float*)d_in[0];
    const float* user_emb   = (const float*)d_in[1];
    const float* weight     = (const float*)d_in[2];
    const float* g1         = (const float*)d_in[3];
    const float* g2         = (const float*)d_in[4];
    const float* g3         = (const float*)d_in[5];
    const int* edge_index  = (const int*)d_in[6];   // (2,E): row0=head(dst), row1=tail(src)
    const int* edge_type   = (const int*)d_in[7];
    const int* uedge_index = (const int*)d_in[8];   // (2,UE)
    const int* uedge_type  = (const int*)d_in[9];
    const int* mat_row     = (const int*)d_in[10];  // user ids
    const int* mat_col     = (const int*)d_in[11];  // item ids

    const int n_entities   = in_sizes[0] / DD;  // 180000
    const int n_user_nodes = in_sizes[1] / DD;  // 150000
    const int nA           = in_sizes[7];       // 1500000 entity edges
    const int nB           = in_sizes[9];       // 1000000 user edges
    const int nM           = in_sizes[10];      // 1500000 interaction edges
    const int n_items      = 50000;
    const int n_users      = 100000;

    const int offA = 0;
    const int offB = n_entities;                // 180000
    const int offC = offB + n_user_nodes;       // 330000
    const int offD = offC + n_items;            // 380000
    const int R    = offD + n_users;            // 480000 total rows
    const int Etot = nA + nB + nM + nM;         // 5.5M edges

    float* out      = (float*)d_out;
    float* user_out = out + (size_t)n_entities * DD;

    // workspace (~105 MB)
    float* ws = (float*)d_ws;
    size_t off = 0;
    float* kg_item = ws + off; off += (size_t)n_items * DD;
    float* ukg     = ws + off; off += (size_t)n_users * DD;
    float* iu      = ws + off; off += (size_t)n_items * DD;
    float* ui      = ws + off; off += (size_t)n_users * DD;
    int* ibase  = (int*)(ws + off);
    int* counts = ibase;            // R
    int* rowptr = ibase + R;        // R
    int* bsums  = ibase + 2 * R;    // 512
    int* pay    = ibase + 2 * R + 512;  // Etot
    int* bounds = pay + Etot;       // NPART+1

    hipMemsetAsync(counts, 0, (size_t)R * sizeof(int), stream);

    // 8 partition-groups x 1024 blocks; group p -> XCD p via round-robin dispatch
    const unsigned gPart = NPART * 1024;
    hist_part<<<gPart, 256, 0, stream>>>(edge_index, uedge_index, mat_col, mat_row,
                                         nA, nB, nM, nM, offA, offB, offC, offD,
                                         R / NPART, counts);
    int nb = (R + 1023) / 1024;   // 469 <= 512
    scan_blocks<<<nb, 256, 0, stream>>>(counts, rowptr, bsums, R);
    scan_sums<<<1, 512, 0, stream>>>(bsums, nb);
    add_offsets<<<(R + 255) / 256, 256, 0, stream>>>(rowptr, bsums, R);
    find_bounds<<<1, 64, 0, stream>>>(rowptr, R, Etot, bounds);
    fill_part<<<gPart, 256, 0, stream>>>(edge_index, edge_index + nA, edge_type,
                                         uedge_index, uedge_index + nB, uedge_type,
                                         mat_col, mat_row,
                                         mat_row, mat_col,
                                         nA, nB, nM, nM, offA, offB, offC, offD,
                                         bounds, rowptr, pay);
    gather_all<<<(R + 3) / 4, 256, 0, stream>>>(entity_emb, user_emb, weight,
                                                rowptr, pay,
                                                kg_item, out, ukg, user_out, iu, ui,
                                                offB, offC, offD, R, n_items, n_users);

    // items: gi = sig(kg@g1.T + iu@g2.T); out = gi*kg + (1-gi)*iu
    gate_fuse_kernel<<<1024, 256, 0, stream>>>(kg_item, iu, g1, g2, out, n_items);
    // users: hi = sig(ui@g2.T + ukg@g3.T); out = hi*ukg + (1-hi)*ui
    gate_fuse_kernel<<<2048, 256, 0, stream>>>(ukg, ui, g3, g2, user_out, n_users);
}